// Round 7
// baseline (80.757 us; speedup 1.0000x reference)
//
#include <hip/hip_runtime.h>
#include <math.h>

#define MAXP 32

template <int CTRL>
__device__ __forceinline__ float dppadd(float v) {
    int t = __builtin_amdgcn_update_dpp(0, __float_as_int(v), CTRL, 0xF, 0xF, false);
    return v + __int_as_float(t);
}
// sum within each 16-lane group (verified on HW in R6)
__device__ __forceinline__ float sum16(float v) {
    v = dppadd<0xB1>(v);    // quad_perm(1,0,3,2)  == xor1
    v = dppadd<0x4E>(v);    // quad_perm(2,3,0,1)  == xor2
    v = dppadd<0x141>(v);   // row_half_mirror     == xor4
    v = dppadd<0x140>(v);   // row_mirror          == xor8
    return v;
}
__device__ __forceinline__ float rdlanef(float v, int l) {
    return __int_as_float(__builtin_amdgcn_readlane(__float_as_int(v), l));
}

// one point, broadcast via readlane->SGPR; padding substitutes point-0 data
// ((P)<np uniform -> s_cmp + s_cselect on SALU pipe, co-issues with VALU)
#define POINT(q, LB, P, mm) do {                                          \
    int xi = __builtin_amdgcn_readlane(__float_as_int((q).x), (LB)+(P));  \
    int yi = __builtin_amdgcn_readlane(__float_as_int((q).y), (LB)+(P));  \
    int zi = __builtin_amdgcn_readlane(__float_as_int((q).z), (LB)+(P));  \
    int wi = __builtin_amdgcn_readlane(__float_as_int((q).w), (LB)+(P));  \
    xi = ((P) < np) ? xi : x0i;                                           \
    yi = ((P) < np) ? yi : y0i;                                           \
    zi = ((P) < np) ? zi : z0i;                                           \
    wi = ((P) < np) ? wi : w0i;                                           \
    float v_ = fmaf(__int_as_float(xi), A, E2);                           \
    v_ = fmaf(__int_as_float(yi), B, v_);                                 \
    v_ = fmaf(__int_as_float(zi), C, v_);                                 \
    v_ = fmaf(__int_as_float(wi), Dk, v_);                                \
    mm = fmaxf(mm, v_);                                                   \
} while (0)

__global__ __launch_bounds__(256, 8) void pfn_kernel(
    const float* __restrict__ voxels,
    const int*   __restrict__ num_points,
    const int*   __restrict__ coords,
    const float* __restrict__ W,
    const float* __restrict__ gammav,
    const float* __restrict__ betav,
    const float* __restrict__ rmean,
    const float* __restrict__ rvar,
    float*       __restrict__ out,
    int N)
{
    const int lane = threadIdx.x & 63;
    const int wid  = threadIdx.x >> 6;
    const int d    = lane;

    // ---- per-lane channel constants (amortized over 4 pillars) ----
    const float w0 = W[0*64+d], w1 = W[1*64+d], w2 = W[2*64+d];
    const float w3 = W[3*64+d], w4 = W[4*64+d], w5 = W[5*64+d];
    const float w6 = W[6*64+d], w7 = W[7*64+d], w8 = W[8*64+d];
    const float inv   = gammav[d] * rsqrtf(rvar[d] + 1e-3f);
    const float shift = fmaf(-rmean[d], inv, betav[d]);
    const float A  = (w0 + w4 + w7) * inv;
    const float B  = (w1 + w5 + w8) * inv;
    const float C  = (w2 + w6) * inv;
    const float Dk = w3 * inv;
    const float P4 = w4*inv, P5 = w5*inv, P6 = w6*inv, P7 = w7*inv, P8 = w8*inv;

    const int base = blockIdx.x * 16 + wid * 4;   // 4 pillars per wave
    if (base >= N) return;

    // ---- per-pillar scalar meta (uniform indices -> s_load) ----
    const int s0 = min(base + 0, N - 1), s1 = min(base + 1, N - 1);
    const int s2 = min(base + 2, N - 1), s3 = min(base + 3, N - 1);
    const int np0 = num_points[s0], np1 = num_points[s1];
    const int np2 = num_points[s2], np3 = num_points[s3];
    const int cx0 = coords[s0*3], cy0 = coords[s0*3+1];
    const int cx1 = coords[s1*3], cy1 = coords[s1*3+1];
    const int cx2 = coords[s2*3], cy2 = coords[s2*3+1];
    const int cx3 = coords[s3*3], cy3 = coords[s3*3+1];

    // ---- point data: lane = point; 2 pillars per dwordx4 load ----
    const int pt = lane & 31;
    const int pilA = (lane >= 32) ? s1 : s0;
    const int pilB = (lane >= 32) ? s3 : s2;
    const float4 g0 = *(const float4*)(voxels + (size_t)pilA * 128 + pt * 4);
    const float4 g1 = *(const float4*)(voxels + (size_t)pilB * 128 + pt * 4);

    // ---- xyz sums over ALL 32 points (ref sums padding too), DPP 16-group ----
    const float bx0 = sum16(g0.x), by0 = sum16(g0.y), bz0 = sum16(g0.z);
    const float bx1 = sum16(g1.x), by1 = sum16(g1.y), bz1 = sum16(g1.z);

    auto pillarBody = [&](const float4& q, int LB, int sp, bool ok,
                          int np, int cxi, int cyi,
                          float sxlo, float sxhi, float sylo, float syhi,
                          float szlo, float szhi) {
        const float cxf = fmaf((float)cxi, 0.2f, 0.1f);    // VX/2 + 0
        const float cyf = fmaf((float)cyi, 0.2f, -25.5f);  // VY/2 - 25.6
        const float E2  = shift - cxf*P7 - cyf*P8;         // mean term deferred

        // point-0 data (always valid: np >= 1) for padded-slot substitution
        const int x0i = __builtin_amdgcn_readlane(__float_as_int(q.x), LB);
        const int y0i = __builtin_amdgcn_readlane(__float_as_int(q.y), LB);
        const int z0i = __builtin_amdgcn_readlane(__float_as_int(q.z), LB);
        const int w0i = __builtin_amdgcn_readlane(__float_as_int(q.w), LB);

        float m0 = -INFINITY, m1 = -INFINITY;
        POINT(q, LB, 0, m0); POINT(q, LB, 1, m1);
        POINT(q, LB, 2, m0); POINT(q, LB, 3, m1);
        POINT(q, LB, 4, m0); POINT(q, LB, 5, m1);
        POINT(q, LB, 6, m0); POINT(q, LB, 7, m1);
        if (np > 8) {
            POINT(q, LB,  8, m0); POINT(q, LB,  9, m1);
            POINT(q, LB, 10, m0); POINT(q, LB, 11, m1);
            POINT(q, LB, 12, m0); POINT(q, LB, 13, m1);
            POINT(q, LB, 14, m0); POINT(q, LB, 15, m1);
        }
        if (np > 16) {
            POINT(q, LB, 16, m0); POINT(q, LB, 17, m1);
            POINT(q, LB, 18, m0); POINT(q, LB, 19, m1);
            POINT(q, LB, 20, m0); POINT(q, LB, 21, m1);
            POINT(q, LB, 22, m0); POINT(q, LB, 23, m1);
        }
        if (np > 24) {
            POINT(q, LB, 24, m0); POINT(q, LB, 25, m1);
            POINT(q, LB, 26, m0); POINT(q, LB, 27, m1);
            POINT(q, LB, 28, m0); POINT(q, LB, 29, m1);
            POINT(q, LB, 30, m0); POINT(q, LB, 31, m1);
        }

        // deferred mean term from 16-group half sums (each FMA reads 1 SGPR)
        float S = sxlo * P4;
        S = fmaf(sxhi, P4, S);
        S = fmaf(sylo, P5, S); S = fmaf(syhi, P5, S);
        S = fmaf(szlo, P6, S); S = fmaf(szhi, P6, S);
        S *= __builtin_amdgcn_rcpf((float)np);

        float mf = fmaxf(m0, m1) - S;
        if (np < MAXP) mf = fmaxf(mf, shift);  // padded points contribute `shift`
        if (ok) out[(size_t)sp * 64 + d] = fmaxf(mf, 0.0f);
    };

    pillarBody(g0,  0, s0, base + 0 < N, np0, cx0, cy0,
               rdlanef(bx0,  0), rdlanef(bx0, 16),
               rdlanef(by0,  0), rdlanef(by0, 16),
               rdlanef(bz0,  0), rdlanef(bz0, 16));
    pillarBody(g0, 32, s1, base + 1 < N, np1, cx1, cy1,
               rdlanef(bx0, 32), rdlanef(bx0, 48),
               rdlanef(by0, 32), rdlanef(by0, 48),
               rdlanef(bz0, 32), rdlanef(bz0, 48));
    pillarBody(g1,  0, s2, base + 2 < N, np2, cx2, cy2,
               rdlanef(bx1,  0), rdlanef(bx1, 16),
               rdlanef(by1,  0), rdlanef(by1, 16),
               rdlanef(bz1,  0), rdlanef(bz1, 16));
    pillarBody(g1, 32, s3, base + 3 < N, np3, cx3, cy3,
               rdlanef(bx1, 32), rdlanef(bx1, 48),
               rdlanef(by1, 32), rdlanef(by1, 48),
               rdlanef(bz1, 32), rdlanef(bz1, 48));
}

extern "C" void kernel_launch(void* const* d_in, const int* in_sizes, int n_in,
                              void* d_out, int out_size, void* d_ws, size_t ws_size,
                              hipStream_t stream) {
    const float* voxels     = (const float*)d_in[0];
    const int*   num_points = (const int*)  d_in[1];
    const int*   coords     = (const int*)  d_in[2];
    const float* W          = (const float*)d_in[3];
    const float* gammav     = (const float*)d_in[4];
    const float* betav      = (const float*)d_in[5];
    const float* rmean      = (const float*)d_in[6];
    const float* rvar       = (const float*)d_in[7];
    float*       out        = (float*)d_out;

    const int N = in_sizes[1];                 // one entry per pillar
    const int blocks = (N + 15) / 16;          // 16 pillars per 256-thr block
    pfn_kernel<<<blocks, 256, 0, stream>>>(voxels, num_points, coords, W,
                                           gammav, betav, rmean, rvar, out, N);
}